// Round 14
// baseline (84.606 us; speedup 1.0000x reference)
//
#include <hip/hip_runtime.h>

typedef unsigned short u16;
typedef __attribute__((ext_vector_type(8))) short bf16x8;
typedef __attribute__((ext_vector_type(4))) float f32x4;
typedef __attribute__((ext_vector_type(8))) unsigned short u16x8;
typedef __attribute__((ext_vector_type(4))) unsigned short u16x4;
typedef __attribute__((ext_vector_type(2))) unsigned short u16x2;

// ---- bf16 helpers (RNE) ----
__device__ __forceinline__ u16 f2b(float f) {
  unsigned u = __builtin_bit_cast(unsigned, f);
  unsigned r = (u + 0x7fffu + ((u >> 16) & 1u)) >> 16;
  return (u16)r;
}
__device__ __forceinline__ float b2f(u16 u) {
  return __builtin_bit_cast(float, ((unsigned)u) << 16);
}
__device__ __forceinline__ void gload16(const void* g, void* l) {
  __builtin_amdgcn_global_load_lds(
      (const __attribute__((address_space(1))) unsigned int*)g,
      (__attribute__((address_space(3))) unsigned int*)l, 16, 0, 0);
}

// ---- fused prep: x cast (2048) | waT (1536) | wpT (1024) | rope tab (256) ----
__global__ __launch_bounds__(256) void k_prep(const float* __restrict__ x,
                                              const float* __restrict__ wa,
                                              const float* __restrict__ wp,
                                              u16* __restrict__ xb,
                                              u16* __restrict__ waT,
                                              u16* __restrict__ wpT,
                                              float2* __restrict__ tab) {
  __shared__ float t[32][33];
  const int idx = blockIdx.x;
  const int tid = threadIdx.x;
  if (idx < 2048) {                       // cast x -> bf16, 8 elems/thread
    int i = idx * 256 + tid;
    float4 v0 = ((const float4*)x)[i * 2];
    float4 v1 = ((const float4*)x)[i * 2 + 1];
    u16x8 o;
    o[0] = f2b(v0.x); o[1] = f2b(v0.y); o[2] = f2b(v0.z); o[3] = f2b(v0.w);
    o[4] = f2b(v1.x); o[5] = f2b(v1.y); o[6] = f2b(v1.z); o[7] = f2b(v1.w);
    ((u16x8*)xb)[i] = o;
    return;
  }
  const int tx = tid & 31, ty = tid >> 5; // transpose tiles, block as (32,8)
  if (idx < 3584) {                       // waT: (1024 x 1536) -> (1536 x 1024)
    int tt = idx - 2048;
    int c0 = (tt % 48) * 32, r0 = (tt / 48) * 32;
    for (int ii = 0; ii < 4; ++ii)
      t[ty + ii * 8][tx] = wa[(size_t)(r0 + ty + ii * 8) * 1536 + c0 + tx];
    __syncthreads();
    for (int ii = 0; ii < 4; ++ii)
      waT[(size_t)(c0 + ty + ii * 8) * 1024 + r0 + tx] = f2b(t[tx][ty + ii * 8]);
    return;
  }
  if (idx < 4608) {                       // wpT: (1024 x 1024) -> (1024 x 1024)
    int tt = idx - 3584;
    int c0 = (tt & 31) * 32, r0 = (tt >> 5) * 32;
    for (int ii = 0; ii < 4; ++ii)
      t[ty + ii * 8][tx] = wp[(size_t)(r0 + ty + ii * 8) * 1024 + c0 + tx];
    __syncthreads();
    for (int ii = 0; ii < 4; ++ii)
      wpT[(size_t)(c0 + ty + ii * 8) * 1024 + r0 + tx] = f2b(t[tx][ty + ii * 8]);
    return;
  }
  {                                       // rope table
    int e = (idx - 4608) * 256 + tid;     // 65536 entries
    int tt = e >> 5, i = e & 31;
    float inv = expf((float)(2 * i) * -0.14391156831f);
    float fr = (float)tt * inv;
    float s, c;
    sincosf(fr, &s, &c);
    tab[tt * 32 + i] = make_float2(c, s);
  }
}

// ---- GEMM1 + fused rope/rms/V-transpose epilogue ----
__global__ __launch_bounds__(256) void k_gemm1(const u16* __restrict__ A,
                                               const u16* __restrict__ Bt,
                                               const float2* __restrict__ tab,
                                               u16* __restrict__ Qb,
                                               u16* __restrict__ Kb,
                                               u16* __restrict__ Vtb) {
  __shared__ u16 smem[64 * 64 + 128 * 64];   // lA | lB; reused as vbuf
  u16* lA = smem;
  u16* lB = smem + 64 * 64;
  const int tid = threadIdx.x;
  const int lane = tid & 63, w = tid >> 6;
  const int wr = w >> 1, wc = w & 1;
  const int la = lane & 15, hi = lane >> 4;
  const int bx = blockIdx.x;
  const int bm0 = blockIdx.y * 64, bn0 = bx * 128;
  const int K = 1024;
  const f32x4 zero = {0.f, 0.f, 0.f, 0.f};
  f32x4 acc[2][4];
#pragma unroll
  for (int m = 0; m < 2; ++m)
#pragma unroll
    for (int n = 0; n < 4; ++n) acc[m][n] = zero;

  const int r = tid >> 3;
  const int s = tid & 7;
  for (int k0 = 0; k0 < K; k0 += 64) {
#pragma unroll
    for (int rr = 0; rr < 2; ++rr) {
      int row = rr * 32 + r;
      gload16(A + (size_t)(bm0 + row) * K + k0 + ((s ^ (row & 7)) << 3),
              &lA[(rr * 256 + tid) * 8]);
    }
#pragma unroll
    for (int rr = 0; rr < 4; ++rr) {
      int row = rr * 32 + r;
      gload16(Bt + (size_t)(bn0 + row) * K + k0 + ((s ^ (row & 7)) << 3),
              &lB[(rr * 256 + tid) * 8]);
    }
    __syncthreads();
#pragma unroll
    for (int kk = 0; kk < 2; ++kk) {
      bf16x8 af[2], bfr[4];
#pragma unroll
      for (int m = 0; m < 2; ++m) {
        int R = wr * 32 + m * 16 + la;
        af[m] = *(const bf16x8*)&lA[R * 64 + (((kk * 4 + hi) ^ (R & 7)) << 3)];
      }
#pragma unroll
      for (int n = 0; n < 4; ++n) {
        int R = wc * 64 + n * 16 + la;
        bfr[n] = *(const bf16x8*)&lB[R * 64 + (((kk * 4 + hi) ^ (R & 7)) << 3)];
      }
#pragma unroll
      for (int m = 0; m < 2; ++m)
#pragma unroll
        for (int n = 0; n < 4; ++n)
          acc[m][n] = __builtin_amdgcn_mfma_f32_16x16x32_bf16(af[m], bfr[n], acc[m][n], 0, 0, 0);
    }
    __syncthreads();
  }
  // ---- fused epilogue ----
  const int tloc = bm0 & 2047;
  const int bb = bm0 >> 11;
  if (bx < 10) {
    const int isq = (bx < 8);
    const int head = isq ? (2 * bx + wc) : (2 * (bx - 8) + wc);
    u16* outp = isq ? Qb : Kb;
    const size_t hbase = ((size_t)(bb * (isq ? 16 : 4) + head) * 2048) * 64;
    const int odd = la & 1;
#pragma unroll
    for (int m = 0; m < 2; ++m)
#pragma unroll
      for (int j = 0; j < 4; ++j) {
        const int tr = tloc + wr * 32 + m * 16 + hi * 4 + j;
        const float2* tb = tab + tr * 32 + (la >> 1);
        float y[4], ssl = 0.f;
#pragma unroll
        for (int n = 0; n < 4; ++n) {
          float v = acc[m][n][j];
          float p = __shfl_xor(v, 1);
          float2 cs = tb[n * 8];
          y[n] = odd ? fmaf(v, cs.x, p * cs.y)
                     : fmaf(v, cs.x, -p * cs.y);
          ssl = fmaf(y[n], y[n], ssl);
        }
        ssl += __shfl_xor(ssl, 1);
        ssl += __shfl_xor(ssl, 2);
        ssl += __shfl_xor(ssl, 4);
        ssl += __shfl_xor(ssl, 8);
        const float sc = rsqrtf(ssl * (1.0f / 64.0f) + 1e-6f);
        u16* rp = outp + hbase + (size_t)tr * 64 + la;
#pragma unroll
        for (int n = 0; n < 4; ++n) rp[n * 16] = f2b(y[n] * sc);
      }
  } else {
    // V block: bf16 into vbuf[64][132] (reuses lA/lB), transposed write
    u16* vbuf = smem;
#pragma unroll
    for (int m = 0; m < 2; ++m)
#pragma unroll
      for (int n = 0; n < 4; ++n)
#pragma unroll
        for (int j = 0; j < 4; ++j)
          vbuf[(wr * 32 + m * 16 + hi * 4 + j) * 132 + wc * 64 + n * 16 + la] =
              f2b(acc[m][n][j]);
    __syncthreads();
    const int dloc = tid >> 1, th = tid & 1;
    const int g = 2 * (bx - 10) + (dloc >> 6);
    const int d = dloc & 63;
    u16* dst = Vtb + ((size_t)(bb * 4 + g) * 64 + d) * 2048 + tloc + th * 32;
#pragma unroll
    for (int c = 0; c < 4; ++c) {
      u16x8 o;
#pragma unroll
      for (int e = 0; e < 8; ++e) o[e] = vbuf[(th * 32 + c * 8 + e) * 132 + dloc];
      *(u16x8*)(dst + c * 8) = o;
    }
  }
}

// ---- GEMM2: C[M,N] f32 = A[M,K](bf16) * Bt[N,K](bf16) ----
template<int OUT_BF16>
__global__ __launch_bounds__(256) void k_gemm_bt(const u16* __restrict__ A,
                                                 const u16* __restrict__ Bt,
                                                 void* __restrict__ Cv,
                                                 int M, int N, int K) {
  __shared__ u16 lA[64 * 64];
  __shared__ u16 lB[128 * 64];
  const int tid = threadIdx.x;
  const int lane = tid & 63, w = tid >> 6;
  const int wr = w >> 1, wc = w & 1;
  const int la = lane & 15, hi = lane >> 4;
  const int bm0 = blockIdx.y * 64, bn0 = blockIdx.x * 128;
  const f32x4 zero = {0.f, 0.f, 0.f, 0.f};
  f32x4 acc[2][4];
#pragma unroll
  for (int m = 0; m < 2; ++m)
#pragma unroll
    for (int n = 0; n < 4; ++n) acc[m][n] = zero;

  const int r = tid >> 3;
  const int s = tid & 7;
  for (int k0 = 0; k0 < K; k0 += 64) {
#pragma unroll
    for (int rr = 0; rr < 2; ++rr) {
      int row = rr * 32 + r;
      gload16(A + (size_t)(bm0 + row) * K + k0 + ((s ^ (row & 7)) << 3),
              &lA[(rr * 256 + tid) * 8]);
    }
#pragma unroll
    for (int rr = 0; rr < 4; ++rr) {
      int row = rr * 32 + r;
      gload16(Bt + (size_t)(bn0 + row) * K + k0 + ((s ^ (row & 7)) << 3),
              &lB[(rr * 256 + tid) * 8]);
    }
    __syncthreads();
#pragma unroll
    for (int kk = 0; kk < 2; ++kk) {
      bf16x8 af[2], bfr[4];
#pragma unroll
      for (int m = 0; m < 2; ++m) {
        int R = wr * 32 + m * 16 + la;
        af[m] = *(const bf16x8*)&lA[R * 64 + (((kk * 4 + hi) ^ (R & 7)) << 3)];
      }
#pragma unroll
      for (int n = 0; n < 4; ++n) {
        int R = wc * 64 + n * 16 + la;
        bfr[n] = *(const bf16x8*)&lB[R * 64 + (((kk * 4 + hi) ^ (R & 7)) << 3)];
      }
#pragma unroll
      for (int m = 0; m < 2; ++m)
#pragma unroll
        for (int n = 0; n < 4; ++n)
          acc[m][n] = __builtin_amdgcn_mfma_f32_16x16x32_bf16(af[m], bfr[n], acc[m][n], 0, 0, 0);
    }
    __syncthreads();
  }
  float* Cf = (float*)Cv;
  u16*   Cb = (u16*)Cv;
#pragma unroll
  for (int m = 0; m < 2; ++m)
#pragma unroll
    for (int n = 0; n < 4; ++n)
#pragma unroll
      for (int j = 0; j < 4; ++j) {
        int row = bm0 + wr * 32 + m * 16 + hi * 4 + j;
        int col = bn0 + wc * 64 + n * 16 + la;
        float v = acc[m][n][j];
        if (OUT_BF16) Cb[(size_t)row * N + col] = f2b(v);
        else          Cf[(size_t)row * N + col] = v;
      }
}

// ---- causal GQA flash attention, v11: 4 qtiles per 512-thread block ----
// grid (32 bh, 8), block 512 (8 waves). Waves 0-3 own qtiles {31-y, y};
// waves 4-7 own {23-y, 8+y}. Unit counts per wave-group are equal (33).
// One K/V staging stream per block (per CU) -> staging halves vs v10;
// barrier-rounds per CU drop 49 -> 32-y. Fixed-max softmax, dbuf LDS,
// one barrier/round, prefetch issued after the barrier.
__global__ __launch_bounds__(512, 1) void k_attn(const u16* __restrict__ Qb,
                                                 const u16* __restrict__ Kb,
                                                 const u16* __restrict__ Vtb,
                                                 u16* __restrict__ Ob) {
  __shared__ u16 lK[2][64][64];
  __shared__ u16 lVt[2][64][64];
  __shared__ u16 lP[8][16][64];
  const int bh = blockIdx.x;
  const int b = bh >> 4, h = bh & 15, g = h >> 2;
  const int y = blockIdx.y;                 // 0..7
  const int tid = threadIdx.x;
  const int lane = tid & 63, w = tid >> 6;  // 8 waves
  const int wl = w & 3, grp = w >> 2;
  const int la = lane & 15, hi = lane >> 4;
  const int qtA = grp ? (23 - y) : (31 - y);
  const int qtB = grp ? (8 + y)  : y;
  const int nt = 32 - y;                    // block-wide rounds

  const u16* Qg  = Qb  + (size_t)(b * 16 + h) * 2048 * 64;
  const u16* Kg  = Kb  + (size_t)(b * 4 + g) * 2048 * 64;
  const u16* Vtg = Vtb + (size_t)(b * 4 + g) * 64 * 2048;

  bf16x8 qfA0, qfA1, qfB0, qfB1;
  {
    const u16* pA = Qg + (size_t)(qtA * 64 + wl * 16 + la) * 64 + hi * 8;
    qfA0 = *(const bf16x8*)pA;
    qfA1 = *(const bf16x8*)(pA + 32);
    const u16* pB = Qg + (size_t)(qtB * 64 + wl * 16 + la) * 64 + hi * 8;
    qfB0 = *(const bf16x8*)pB;
    qfB1 = *(const bf16x8*)(pB + 32);
  }
  const float C = 0.18033688011f;      // 0.125 * log2(e)
  const float nmc = -64.0f * C;        // fixed max (|q|=|k|=8 after RMS)
  float lA_ = 0.f, lB_ = 0.f;
  const f32x4 zero = {0.f, 0.f, 0.f, 0.f};
  f32x4 aoA[4], aoB[4];
#pragma unroll
  for (int f = 0; f < 4; ++f) { aoA[f] = zero; aoB[f] = zero; }

  const int sr = tid >> 3;             // staging row 0..63 (512 threads)
  const int ss = (tid & 7) * 8;
  const int sw = ss ^ ((sr & 7) << 3);
  const int rcc = (hi * 8) ^ ((la & 7) << 3);

  {                                    // prologue: stage tile 0
    u16x8 k0 = *(const u16x8*)(Kg  + (size_t)sr * 64 + ss);
    u16x8 v0 = *(const u16x8*)(Vtg + (size_t)sr * 2048 + ss);
    *(u16x8*)(&lK[0][sr][sw])  = k0;
    *(u16x8*)(&lVt[0][sr][sw]) = v0;
  }

  for (int kt = 0; kt < nt; ++kt) {
    const int cur = kt & 1;
    __syncthreads();                   // buf[cur] ready (written last iter)

    // prefetch next tile (issued after barrier; drains at trailing ds_write)
    u16x8 kreg, vreg;
    if (kt + 1 < nt) {
      int kv = (kt + 1) * 64;
      kreg = *(const u16x8*)(Kg  + (size_t)(kv + sr) * 64 + ss);
      vreg = *(const u16x8*)(Vtg + (size_t)sr * 2048 + kv + ss);
    }

    if (kt <= qtA) {
      // K and V fragments: LDS -> registers ONCE, shared by A and B
      bf16x8 kb[4][2], vb[4][2];
#pragma unroll
      for (int n = 0; n < 4; ++n) {
        const u16* kr = &lK[cur][n * 16 + la][0];
        kb[n][0] = *(const bf16x8*)(kr + rcc);
        kb[n][1] = *(const bf16x8*)(kr + (rcc ^ 32));
        const u16* vr = &lVt[cur][n * 16 + la][0];
        vb[n][0] = *(const bf16x8*)(vr + rcc);
        vb[n][1] = *(const bf16x8*)(vr + (rcc ^ 32));
      }

      // ---------------- qtile A ----------------
      {
        float z_[4][4];
        __builtin_amdgcn_s_setprio(1);
#pragma unroll
        for (int n = 0; n < 4; ++n) {
          f32x4 z = zero;
          z = __builtin_amdgcn_mfma_f32_16x16x32_bf16(kb[n][0], qfA0, z, 0, 0, 0);
          z = __builtin_amdgcn_mfma_f32_16x16x32_bf16(kb[n][1], qfA1, z, 0, 0, 0);
#pragma unroll
          for (int j = 0; j < 4; ++j) z_[n][j] = z[j];
        }
        __builtin_amdgcn_s_setprio(0);
        if (kt == qtA) {               // diagonal (tile-local coords)
#pragma unroll
          for (int n = 0; n < 4; ++n)
#pragma unroll
            for (int j = 0; j < 4; ++j)
              if (n * 16 + hi * 4 + j > wl * 16 + la) z_[n][j] = -3e38f;
        }
        float rs = 0.f;
#pragma unroll
        for (int n = 0; n < 4; ++n)
#pragma unroll
          for (int j = 0; j < 4; ++j) {
            float pe = __builtin_amdgcn_exp2f(fmaf(z_[n][j], C, nmc));
            z_[n][j] = pe;
            rs += pe;
          }
        lA_ += rs;
#pragma unroll
        for (int n = 0; n < 4; ++n) {
          unsigned w0, w1;
          asm("v_cvt_pk_bf16_f32 %0, %1, %2" : "=v"(w0) : "v"(z_[n][0]), "v"(z_[n][1]));
          asm("v_cvt_pk_bf16_f32 %0, %1, %2" : "=v"(w1) : "v"(z_[n][2]), "v"(z_[n][3]));
          uint2 pw; pw.x = w0; pw.y = w1;
          *(uint2*)(&lP[w][la][(n * 16 + hi * 4) ^ ((la & 7) << 3)]) = pw;
        }
        const u16* pr = &lP[w][la][0];
        bf16x8 pa0 = *(const bf16x8*)(pr + rcc);
        bf16x8 pa1 = *(const bf16x8*)(pr + (rcc ^ 32));
        __builtin_amdgcn_s_setprio(1);
#pragma unroll
        for (int f = 0; f < 4; ++f) {
          aoA[f] = __builtin_amdgcn_mfma_f32_16x16x32_bf16(pa0, vb[f][0], aoA[f], 0, 0, 0);
          aoA[f] = __builtin_amdgcn_mfma_f32_16x16x32_bf16(pa1, vb[f][1], aoA[f], 0, 0, 0);
        }
        __builtin_amdgcn_s_setprio(0);
      }

      // ---------------- qtile B (prefix of A's range) ----------------
      if (kt <= qtB) {
        float z_[4][4];
        __builtin_amdgcn_s_setprio(1);
#pragma unroll
        for (int n = 0; n < 4; ++n) {
          f32x4 z = zero;
          z = __builtin_amdgcn_mfma_f32_16x16x32_bf16(kb[n][0], qfB0, z, 0, 0, 0);
          z = __builtin_amdgcn_mfma_f32_16x16x32_bf16(kb[n][1], qfB1, z, 0, 0, 0);
#pragma unroll
          for (int j = 0; j < 4; ++j) z_[n][j] = z[j];
        }
        __builtin_amdgcn_s_setprio(0);
        if (kt == qtB) {               // diagonal
#pragma unroll
          for (int n = 0; n < 4; ++n)
#pragma unroll
            for (int j = 0; j < 4; ++j)
              if (n * 16 + hi * 4 + j > wl * 16 + la) z_[n][j] = -3e38f;
        }
        float rs = 0.f;
#pragma unroll
        for (int n = 0; n < 4; ++n)
#pragma unroll
          for (int j = 0; j < 4; ++j) {
            float pe = __builtin_amdgcn_exp2f(fmaf(z_[n][j], C, nmc));
            z_[n][j] = pe;
            rs += pe;
          }
        lB_ += rs;
#pragma unroll
        for (int n = 0; n < 4; ++n) {
          unsigned w0, w1;
          asm("v_cvt_pk_bf16_f32 %0, %1, %2" : "=v"(w0) : "v"(z_[n][0]), "v"(z_[n][1]));
          asm("v_cvt_pk_bf16_f32 %0, %1, %2" : "=v"(w1) : "v"(z_[n][2]), "v"(z_[n][3]));
          uint2 pw; pw.x = w0; pw.y = w1;
          *(uint2*)(&lP[w][la][(n * 16 + hi * 4) ^ ((la & 7) << 3)]) = pw;
        }
        const u16* pr = &lP[w][la][0];
        bf16x8 pa0 = *(const bf16x8*)(pr + rcc);
        bf16x8 pa1 = *(const bf16x8*)(pr + (rcc ^ 32));
        __builtin_amdgcn_s_setprio(1);
#pragma unroll
        for (int f = 0; f < 4; ++f) {
          aoB[f] = __builtin_amdgcn_mfma_f32_16x16x32_bf16(pa0, vb[f][0], aoB[f], 0, 0, 0);
          aoB[f] = __builtin_amdgcn_mfma_f32_16x16x32_bf16(pa1, vb[f][1], aoB[f], 0, 0, 0);
        }
        __builtin_amdgcn_s_setprio(0);
      }
    }

    if (kt + 1 < nt) {                 // write next tile into other buffer
      const int nxt = cur ^ 1;
      *(u16x8*)(&lK[nxt][sr][sw])  = kreg;
      *(u16x8*)(&lVt[nxt][sr][sw]) = vreg;
    }
  }

  // epilogues: reduce l across hi-copies once, normalize, store
  lA_ += __shfl_xor(lA_, 16, 64);
  lA_ += __shfl_xor(lA_, 32, 64);
  lB_ += __shfl_xor(lB_, 16, 64);
  lB_ += __shfl_xor(lB_, 32, 64);
  {
    float linv[4];
#pragma unroll
    for (int j = 0; j < 4; ++j) linv[j] = 1.0f / __shfl(lA_, 4 * hi + j, 64);
#pragma unroll
    for (int f = 0; f < 4; ++f)
#pragma unroll
      for (int j = 0; j < 4; ++j) {
        int row = qtA * 64 + wl * 16 + hi * 4 + j;
        Ob[((size_t)(b * 2048 + row)) * 1024 + h * 64 + f * 16 + la] =
            f2b(aoA[f][j] * linv[j]);
      }
  }
  {
    float linv[4];
#pragma unroll
    for (int j = 0; j < 4; ++j) linv[j] = 1.0f / __shfl(lB_, 4 * hi + j, 64);
#pragma unroll
    for (int f = 0; f < 4; ++f)
#pragma unroll
      for (int j = 0; j < 4; ++j) {
        int row = qtB * 64 + wl * 16 + hi * 4 + j;
        Ob[((size_t)(b * 2048 + row)) * 1024 + h * 64 + f * 16 + la] =
            f2b(aoB[f][j] * linv[j]);
      }
  }
}

extern "C" void kernel_launch(void* const* d_in, const int* in_sizes, int n_in,
                              void* d_out, int out_size, void* d_ws, size_t ws_size,
                              hipStream_t stream) {
  const float* x  = (const float*)d_in[0];   // (2,2048,1024) f32
  const float* wa = (const float*)d_in[1];   // (1024,1536)  f32
  const float* wp = (const float*)d_in[2];   // (1024,1024)  f32
  float* out = (float*)d_out;                // (2,2048,1024) f32
  char* ws = (char*)d_ws;
  u16* xb    = (u16*)(ws + 0);          // 4096x1024 bf16
  u16* waT   = (u16*)(ws + 8388608);    // 1536x1024 bf16
  u16* wpT   = (u16*)(ws + 11534336);   // 1024x1024 bf16
  u16* Qb    = (u16*)(ws + 26214400);   // [2][16][2048][64] bf16
  u16* Kb    = (u16*)(ws + 34603008);   // [2][4][2048][64] bf16
  u16* Vtb   = (u16*)(ws + 36700160);   // [2][4][64][2048] bf16
  u16* Ob    = (u16*)(ws + 38797312);   // 4096x1024 bf16
  float2* rt = (float2*)(ws + 47185920); // 2048x32 float2 (512KB)

  k_prep<<<4864, 256, 0, stream>>>(x, wa, wp, xb, waT, wpT, rt);
  k_gemm1<<<dim3(12, 64), 256, 0, stream>>>(xb, waT, rt, Qb, Kb, Vtb);
  k_attn<<<dim3(32, 8), 512, 0, stream>>>(Qb, Kb, Vtb, Ob);
  k_gemm_bt<0><<<dim3(8, 64), 256, 0, stream>>>(Ob, wpT, out, 4096, 1024, 1024);
}

// Round 15
// 79.199 us; speedup vs baseline: 1.0683x; 1.0683x over previous
//
#include <hip/hip_runtime.h>

typedef unsigned short u16;
typedef __attribute__((ext_vector_type(8))) short bf16x8;
typedef __attribute__((ext_vector_type(4))) float f32x4;
typedef __attribute__((ext_vector_type(8))) unsigned short u16x8;
typedef __attribute__((ext_vector_type(4))) unsigned short u16x4;
typedef __attribute__((ext_vector_type(2))) unsigned short u16x2;

// ---- bf16 helpers (RNE) ----
__device__ __forceinline__ u16 f2b(float f) {
  unsigned u = __builtin_bit_cast(unsigned, f);
  unsigned r = (u + 0x7fffu + ((u >> 16) & 1u)) >> 16;
  return (u16)r;
}
__device__ __forceinline__ float b2f(u16 u) {
  return __builtin_bit_cast(float, ((unsigned)u) << 16);
}
__device__ __forceinline__ void gload16(const void* g, void* l) {
  __builtin_amdgcn_global_load_lds(
      (const __attribute__((address_space(1))) unsigned int*)g,
      (__attribute__((address_space(3))) unsigned int*)l, 16, 0, 0);
}

// ---- fused prep: x cast (2048) | waT (1536) | wpT (1024) | rope tab (256) ----
__global__ __launch_bounds__(256) void k_prep(const float* __restrict__ x,
                                              const float* __restrict__ wa,
                                              const float* __restrict__ wp,
                                              u16* __restrict__ xb,
                                              u16* __restrict__ waT,
                                              u16* __restrict__ wpT,
                                              float2* __restrict__ tab) {
  __shared__ float t[32][33];
  const int idx = blockIdx.x;
  const int tid = threadIdx.x;
  if (idx < 2048) {                       // cast x -> bf16, 8 elems/thread
    int i = idx * 256 + tid;
    float4 v0 = ((const float4*)x)[i * 2];
    float4 v1 = ((const float4*)x)[i * 2 + 1];
    u16x8 o;
    o[0] = f2b(v0.x); o[1] = f2b(v0.y); o[2] = f2b(v0.z); o[3] = f2b(v0.w);
    o[4] = f2b(v1.x); o[5] = f2b(v1.y); o[6] = f2b(v1.z); o[7] = f2b(v1.w);
    ((u16x8*)xb)[i] = o;
    return;
  }
  const int tx = tid & 31, ty = tid >> 5; // transpose tiles, block as (32,8)
  if (idx < 3584) {                       // waT: (1024 x 1536) -> (1536 x 1024)
    int tt = idx - 2048;
    int c0 = (tt % 48) * 32, r0 = (tt / 48) * 32;
    for (int ii = 0; ii < 4; ++ii)
      t[ty + ii * 8][tx] = wa[(size_t)(r0 + ty + ii * 8) * 1536 + c0 + tx];
    __syncthreads();
    for (int ii = 0; ii < 4; ++ii)
      waT[(size_t)(c0 + ty + ii * 8) * 1024 + r0 + tx] = f2b(t[tx][ty + ii * 8]);
    return;
  }
  if (idx < 4608) {                       // wpT: (1024 x 1024) -> (1024 x 1024)
    int tt = idx - 3584;
    int c0 = (tt & 31) * 32, r0 = (tt >> 5) * 32;
    for (int ii = 0; ii < 4; ++ii)
      t[ty + ii * 8][tx] = wp[(size_t)(r0 + ty + ii * 8) * 1024 + c0 + tx];
    __syncthreads();
    for (int ii = 0; ii < 4; ++ii)
      wpT[(size_t)(c0 + ty + ii * 8) * 1024 + r0 + tx] = f2b(t[tx][ty + ii * 8]);
    return;
  }
  {                                       // rope table
    int e = (idx - 4608) * 256 + tid;     // 65536 entries
    int tt = e >> 5, i = e & 31;
    float inv = expf((float)(2 * i) * -0.14391156831f);
    float fr = (float)tt * inv;
    float s, c;
    sincosf(fr, &s, &c);
    tab[tt * 32 + i] = make_float2(c, s);
  }
}

// ---- GEMM1 + fused rope/rms/V-transpose epilogue ----
// 1D grid 768, XCD-swizzled: dispatch d -> o = (d%8)*96 + d/8, so each XCD
// owns 8 consecutive A-row panels (1MB) + B (3MB) in its L2.
__global__ __launch_bounds__(256) void k_gemm1(const u16* __restrict__ A,
                                               const u16* __restrict__ Bt,
                                               const float2* __restrict__ tab,
                                               u16* __restrict__ Qb,
                                               u16* __restrict__ Kb,
                                               u16* __restrict__ Vtb) {
  __shared__ u16 smem[64 * 64 + 128 * 64];   // lA | lB; reused as vbuf
  u16* lA = smem;
  u16* lB = smem + 64 * 64;
  const int tid = threadIdx.x;
  const int lane = tid & 63, w = tid >> 6;
  const int wr = w >> 1, wc = w & 1;
  const int la = lane & 15, hi = lane >> 4;
  const int o = ((int)blockIdx.x % 8) * 96 + (int)blockIdx.x / 8;
  const int bx = o % 12;
  const int bm0 = (o / 12) * 64, bn0 = bx * 128;
  const int K = 1024;
  const f32x4 zero = {0.f, 0.f, 0.f, 0.f};
  f32x4 acc[2][4];
#pragma unroll
  for (int m = 0; m < 2; ++m)
#pragma unroll
    for (int n = 0; n < 4; ++n) acc[m][n] = zero;

  const int r = tid >> 3;
  const int s = tid & 7;
  for (int k0 = 0; k0 < K; k0 += 64) {
#pragma unroll
    for (int rr = 0; rr < 2; ++rr) {
      int row = rr * 32 + r;
      gload16(A + (size_t)(bm0 + row) * K + k0 + ((s ^ (row & 7)) << 3),
              &lA[(rr * 256 + tid) * 8]);
    }
#pragma unroll
    for (int rr = 0; rr < 4; ++rr) {
      int row = rr * 32 + r;
      gload16(Bt + (size_t)(bn0 + row) * K + k0 + ((s ^ (row & 7)) << 3),
              &lB[(rr * 256 + tid) * 8]);
    }
    __syncthreads();
#pragma unroll
    for (int kk = 0; kk < 2; ++kk) {
      bf16x8 af[2], bfr[4];
#pragma unroll
      for (int m = 0; m < 2; ++m) {
        int R = wr * 32 + m * 16 + la;
        af[m] = *(const bf16x8*)&lA[R * 64 + (((kk * 4 + hi) ^ (R & 7)) << 3)];
      }
#pragma unroll
      for (int n = 0; n < 4; ++n) {
        int R = wc * 64 + n * 16 + la;
        bfr[n] = *(const bf16x8*)&lB[R * 64 + (((kk * 4 + hi) ^ (R & 7)) << 3)];
      }
#pragma unroll
      for (int m = 0; m < 2; ++m)
#pragma unroll
        for (int n = 0; n < 4; ++n)
          acc[m][n] = __builtin_amdgcn_mfma_f32_16x16x32_bf16(af[m], bfr[n], acc[m][n], 0, 0, 0);
    }
    __syncthreads();
  }
  // ---- fused epilogue ----
  const int tloc = bm0 & 2047;
  const int bb = bm0 >> 11;
  if (bx < 10) {
    const int isq = (bx < 8);
    const int head = isq ? (2 * bx + wc) : (2 * (bx - 8) + wc);
    u16* outp = isq ? Qb : Kb;
    const size_t hbase = ((size_t)(bb * (isq ? 16 : 4) + head) * 2048) * 64;
    const int odd = la & 1;
#pragma unroll
    for (int m = 0; m < 2; ++m)
#pragma unroll
      for (int j = 0; j < 4; ++j) {
        const int tr = tloc + wr * 32 + m * 16 + hi * 4 + j;
        const float2* tb = tab + tr * 32 + (la >> 1);
        float y[4], ssl = 0.f;
#pragma unroll
        for (int n = 0; n < 4; ++n) {
          float v = acc[m][n][j];
          float p = __shfl_xor(v, 1);
          float2 cs = tb[n * 8];
          y[n] = odd ? fmaf(v, cs.x, p * cs.y)
                     : fmaf(v, cs.x, -p * cs.y);
          ssl = fmaf(y[n], y[n], ssl);
        }
        ssl += __shfl_xor(ssl, 1);
        ssl += __shfl_xor(ssl, 2);
        ssl += __shfl_xor(ssl, 4);
        ssl += __shfl_xor(ssl, 8);
        const float sc = rsqrtf(ssl * (1.0f / 64.0f) + 1e-6f);
        u16* rp = outp + hbase + (size_t)tr * 64 + la;
#pragma unroll
        for (int n = 0; n < 4; ++n) rp[n * 16] = f2b(y[n] * sc);
      }
  } else {
    // V block: bf16 into vbuf[64][132] (reuses lA/lB), transposed write
    u16* vbuf = smem;
#pragma unroll
    for (int m = 0; m < 2; ++m)
#pragma unroll
      for (int n = 0; n < 4; ++n)
#pragma unroll
        for (int j = 0; j < 4; ++j)
          vbuf[(wr * 32 + m * 16 + hi * 4 + j) * 132 + wc * 64 + n * 16 + la] =
              f2b(acc[m][n][j]);
    __syncthreads();
    const int dloc = tid >> 1, th = tid & 1;
    const int g = 2 * (bx - 10) + (dloc >> 6);
    const int d = dloc & 63;
    u16* dst = Vtb + ((size_t)(bb * 4 + g) * 64 + d) * 2048 + tloc + th * 32;
#pragma unroll
    for (int c = 0; c < 4; ++c) {
      u16x8 o2;
#pragma unroll
      for (int e = 0; e < 8; ++e) o2[e] = vbuf[(th * 32 + c * 8 + e) * 132 + dloc];
      *(u16x8*)(dst + c * 8) = o2;
    }
  }
}

// ---- GEMM2: C[M,N] f32 = A[M,K](bf16) * Bt[N,K](bf16) ----
// 1D grid 512, XCD-swizzled: o = (d%8)*64 + d/8.
template<int OUT_BF16>
__global__ __launch_bounds__(256) void k_gemm_bt(const u16* __restrict__ A,
                                                 const u16* __restrict__ Bt,
                                                 void* __restrict__ Cv,
                                                 int M, int N, int K) {
  __shared__ u16 lA[64 * 64];
  __shared__ u16 lB[128 * 64];
  const int tid = threadIdx.x;
  const int lane = tid & 63, w = tid >> 6;
  const int wr = w >> 1, wc = w & 1;
  const int la = lane & 15, hi = lane >> 4;
  const int o = ((int)blockIdx.x % 8) * 64 + (int)blockIdx.x / 8;
  const int bm0 = (o >> 3) * 64, bn0 = (o & 7) * 128;
  const f32x4 zero = {0.f, 0.f, 0.f, 0.f};
  f32x4 acc[2][4];
#pragma unroll
  for (int m = 0; m < 2; ++m)
#pragma unroll
    for (int n = 0; n < 4; ++n) acc[m][n] = zero;

  const int r = tid >> 3;
  const int s = tid & 7;
  for (int k0 = 0; k0 < K; k0 += 64) {
#pragma unroll
    for (int rr = 0; rr < 2; ++rr) {
      int row = rr * 32 + r;
      gload16(A + (size_t)(bm0 + row) * K + k0 + ((s ^ (row & 7)) << 3),
              &lA[(rr * 256 + tid) * 8]);
    }
#pragma unroll
    for (int rr = 0; rr < 4; ++rr) {
      int row = rr * 32 + r;
      gload16(Bt + (size_t)(bn0 + row) * K + k0 + ((s ^ (row & 7)) << 3),
              &lB[(rr * 256 + tid) * 8]);
    }
    __syncthreads();
#pragma unroll
    for (int kk = 0; kk < 2; ++kk) {
      bf16x8 af[2], bfr[4];
#pragma unroll
      for (int m = 0; m < 2; ++m) {
        int R = wr * 32 + m * 16 + la;
        af[m] = *(const bf16x8*)&lA[R * 64 + (((kk * 4 + hi) ^ (R & 7)) << 3)];
      }
#pragma unroll
      for (int n = 0; n < 4; ++n) {
        int R = wc * 64 + n * 16 + la;
        bfr[n] = *(const bf16x8*)&lB[R * 64 + (((kk * 4 + hi) ^ (R & 7)) << 3)];
      }
#pragma unroll
      for (int m = 0; m < 2; ++m)
#pragma unroll
        for (int n = 0; n < 4; ++n)
          acc[m][n] = __builtin_amdgcn_mfma_f32_16x16x32_bf16(af[m], bfr[n], acc[m][n], 0, 0, 0);
    }
    __syncthreads();
  }
  float* Cf = (float*)Cv;
  u16*   Cb = (u16*)Cv;
#pragma unroll
  for (int m = 0; m < 2; ++m)
#pragma unroll
    for (int n = 0; n < 4; ++n)
#pragma unroll
      for (int j = 0; j < 4; ++j) {
        int row = bm0 + wr * 32 + m * 16 + hi * 4 + j;
        int col = bn0 + wc * 64 + n * 16 + la;
        float v = acc[m][n][j];
        if (OUT_BF16) Cb[(size_t)row * N + col] = f2b(v);
        else          Cf[(size_t)row * N + col] = v;
      }
}

// ---- causal GQA flash attention, v10x: v10 + XCD-aware (b,g) placement ----
// 1D grid 512: dispatch d -> XCD d%8 owns (b,g) = d%8, so each XCD's L2
// holds exactly its 512KB K/V stream. Decomposition: bg8=d%8, r2=d/8,
// hh=r2%4, y=r2/4. CU pairing preserved: d and d+256 co-reside (y, y+8).
// Block = 4 waves x 16 q-rows, TWO qtiles in one kv loop (B prefix of A),
// shared K/V register fragments, fixed-max softmax, dbuf LDS, 1 barrier.
__global__ __launch_bounds__(256, 2) void k_attn(const u16* __restrict__ Qb,
                                                 const u16* __restrict__ Kb,
                                                 const u16* __restrict__ Vtb,
                                                 u16* __restrict__ Ob) {
  __shared__ u16 lK[2][64][64];
  __shared__ u16 lVt[2][64][64];
  __shared__ u16 lP[4][16][64];
  const int d = blockIdx.x;
  const int bg8 = d & 7, r2 = d >> 3;
  const int b = bg8 >> 2, g = bg8 & 3;
  const int h = g * 4 + (r2 & 3);
  const int y = r2 >> 2;                    // 0..15
  int qtA, qtB;
  if (y < 8) { qtA = 31 - y; qtB = y; }
  else       { qtA = y + 8;  qtB = 23 - y; }
  const int ntA = qtA + 1;
  const int tid = threadIdx.x;
  const int lane = tid & 63, w = tid >> 6;
  const int la = lane & 15, hi = lane >> 4;

  const u16* Qg  = Qb  + (size_t)(b * 16 + h) * 2048 * 64;
  const u16* Kg  = Kb  + (size_t)(b * 4 + g) * 2048 * 64;
  const u16* Vtg = Vtb + (size_t)(b * 4 + g) * 64 * 2048;

  bf16x8 qfA0, qfA1, qfB0, qfB1;
  {
    const u16* pA = Qg + (size_t)(qtA * 64 + w * 16 + la) * 64 + hi * 8;
    qfA0 = *(const bf16x8*)pA;
    qfA1 = *(const bf16x8*)(pA + 32);
    const u16* pB = Qg + (size_t)(qtB * 64 + w * 16 + la) * 64 + hi * 8;
    qfB0 = *(const bf16x8*)pB;
    qfB1 = *(const bf16x8*)(pB + 32);
  }
  const float C = 0.18033688011f;      // 0.125 * log2(e)
  const float nmc = -64.0f * C;        // fixed max (|q|=|k|=8 after RMS)
  float lA_ = 0.f, lB_ = 0.f;
  const f32x4 zero = {0.f, 0.f, 0.f, 0.f};
  f32x4 aoA[4], aoB[4];
#pragma unroll
  for (int f = 0; f < 4; ++f) { aoA[f] = zero; aoB[f] = zero; }

  const int sr = tid >> 3;             // staging row 0..31 (and +32)
  const int ss = (tid & 7) * 8;
  const int sw = ss ^ ((sr & 7) << 3);
  const int rcc = (hi * 8) ^ ((la & 7) << 3);

  {                                    // prologue: stage tile 0
    u16x8 k0 = *(const u16x8*)(Kg  + (size_t)sr * 64 + ss);
    u16x8 k1 = *(const u16x8*)(Kg  + (size_t)(sr + 32) * 64 + ss);
    u16x8 q0 = *(const u16x8*)(Vtg + (size_t)sr * 2048 + ss);
    u16x8 q1 = *(const u16x8*)(Vtg + (size_t)(sr + 32) * 2048 + ss);
    *(u16x8*)(&lK[0][sr][sw])       = k0;
    *(u16x8*)(&lK[0][sr + 32][sw])  = k1;
    *(u16x8*)(&lVt[0][sr][sw])      = q0;
    *(u16x8*)(&lVt[0][sr + 32][sw]) = q1;
  }

  for (int kt = 0; kt < ntA; ++kt) {
    const int cur = kt & 1;
    __syncthreads();                   // buf[cur] ready (written last iter)

    // prefetch next tile (issued after barrier; drains at trailing ds_write)
    u16x8 kreg0, kreg1, vreg0, vreg1;
    if (kt + 1 < ntA) {
      int kv = (kt + 1) * 64;
      kreg0 = *(const u16x8*)(Kg  + (size_t)(kv + sr) * 64 + ss);
      kreg1 = *(const u16x8*)(Kg  + (size_t)(kv + sr + 32) * 64 + ss);
      vreg0 = *(const u16x8*)(Vtg + (size_t)sr * 2048 + kv + ss);
      vreg1 = *(const u16x8*)(Vtg + (size_t)(sr + 32) * 2048 + kv + ss);
    }

    // K and V fragments: LDS -> registers ONCE, shared by A and B
    bf16x8 kb[4][2], vb[4][2];
#pragma unroll
    for (int n = 0; n < 4; ++n) {
      const u16* kr = &lK[cur][n * 16 + la][0];
      kb[n][0] = *(const bf16x8*)(kr + rcc);
      kb[n][1] = *(const bf16x8*)(kr + (rcc ^ 32));
      const u16* vr = &lVt[cur][n * 16 + la][0];
      vb[n][0] = *(const bf16x8*)(vr + rcc);
      vb[n][1] = *(const bf16x8*)(vr + (rcc ^ 32));
    }

    // ---------------- qtile A ----------------
    {
      float z_[4][4];
      __builtin_amdgcn_s_setprio(1);
#pragma unroll
      for (int n = 0; n < 4; ++n) {
        f32x4 z = zero;
        z = __builtin_amdgcn_mfma_f32_16x16x32_bf16(kb[n][0], qfA0, z, 0, 0, 0);
        z = __builtin_amdgcn_mfma_f32_16x16x32_bf16(kb[n][1], qfA1, z, 0, 0, 0);
#pragma unroll
        for (int j = 0; j < 4; ++j) z_[n][j] = z[j];
      }
      __builtin_amdgcn_s_setprio(0);
      if (kt == qtA) {                 // diagonal (tile-local coords)
#pragma unroll
        for (int n = 0; n < 4; ++n)
#pragma unroll
          for (int j = 0; j < 4; ++j)
            if (n * 16 + hi * 4 + j > w * 16 + la) z_[n][j] = -3e38f;
      }
      float rs = 0.f;
#pragma unroll
      for (int n = 0; n < 4; ++n)
#pragma unroll
        for (int j = 0; j < 4; ++j) {
          float pe = __builtin_amdgcn_exp2f(fmaf(z_[n][j], C, nmc));
          z_[n][j] = pe;
          rs += pe;
        }
      lA_ += rs;
#pragma unroll
      for (int n = 0; n < 4; ++n) {
        unsigned w0, w1;
        asm("v_cvt_pk_bf16_f32 %0, %1, %2" : "=v"(w0) : "v"(z_[n][0]), "v"(z_[n][1]));
        asm("v_cvt_pk_bf16_f32 %0, %1, %2" : "=v"(w1) : "v"(z_[n][2]), "v"(z_[n][3]));
        uint2 pw; pw.x = w0; pw.y = w1;
        *(uint2*)(&lP[w][la][(n * 16 + hi * 4) ^ ((la & 7) << 3)]) = pw;
      }
      const u16* pr = &lP[w][la][0];
      bf16x8 pa0 = *(const bf16x8*)(pr + rcc);
      bf16x8 pa1 = *(const bf16x8*)(pr + (rcc ^ 32));
      __builtin_amdgcn_s_setprio(1);
#pragma unroll
      for (int f = 0; f < 4; ++f) {
        aoA[f] = __builtin_amdgcn_mfma_f32_16x16x32_bf16(pa0, vb[f][0], aoA[f], 0, 0, 0);
        aoA[f] = __builtin_amdgcn_mfma_f32_16x16x32_bf16(pa1, vb[f][1], aoA[f], 0, 0, 0);
      }
      __builtin_amdgcn_s_setprio(0);
    }

    // ---------------- qtile B (prefix of A's range) ----------------
    if (kt <= qtB) {
      float z_[4][4];
      __builtin_amdgcn_s_setprio(1);
#pragma unroll
      for (int n = 0; n < 4; ++n) {
        f32x4 z = zero;
        z = __builtin_amdgcn_mfma_f32_16x16x32_bf16(kb[n][0], qfB0, z, 0, 0, 0);
        z = __builtin_amdgcn_mfma_f32_16x16x32_bf16(kb[n][1], qfB1, z, 0, 0, 0);
#pragma unroll
        for (int j = 0; j < 4; ++j) z_[n][j] = z[j];
      }
      __builtin_amdgcn_s_setprio(0);
      if (kt == qtB) {                 // diagonal
#pragma unroll
        for (int n = 0; n < 4; ++n)
#pragma unroll
          for (int j = 0; j < 4; ++j)
            if (n * 16 + hi * 4 + j > w * 16 + la) z_[n][j] = -3e38f;
      }
      float rs = 0.f;
#pragma unroll
      for (int n = 0; n < 4; ++n)
#pragma unroll
        for (int j = 0; j < 4; ++j) {
          float pe = __builtin_amdgcn_exp2f(fmaf(z_[n][j], C, nmc));
          z_[n][j] = pe;
          rs += pe;
        }
      lB_ += rs;
#pragma unroll
      for (int n = 0; n < 4; ++n) {
        unsigned w0, w1;
        asm("v_cvt_pk_bf16_f32 %0, %1, %2" : "=v"(w0) : "v"(z_[n][0]), "v"(z_[n][1]));
        asm("v_cvt_pk_bf16_f32 %0, %1, %2" : "=v"(w1) : "v"(z_[n][2]), "v"(z_[n][3]));
        uint2 pw; pw.x = w0; pw.y = w1;
        *(uint2*)(&lP[w][la][(n * 16 + hi * 4) ^ ((la & 7) << 3)]) = pw;
      }
      const u16* pr = &lP[w][la][0];
      bf16x8 pa0 = *(const bf16x8*)(pr + rcc);
      bf16x8 pa1 = *(const bf16x8*)(pr + (rcc ^ 32));
      __builtin_amdgcn_s_setprio(1);
#pragma unroll
      for (int f = 0; f < 4; ++f) {
        aoB[f] = __builtin_amdgcn_mfma_f32_16x16x32_bf16(pa0, vb[f][0], aoB[f], 0, 0, 0);
        aoB[f] = __builtin_amdgcn_mfma_f32_16x16x32_bf16(pa1, vb[f][1], aoB[f], 0, 0, 0);
      }
      __builtin_amdgcn_s_setprio(0);
    }

    if (kt + 1 < ntA) {                // write next tile into other buffer
      const int nxt = cur ^ 1;
      *(u16x8*)(&lK[nxt][sr][sw])       = kreg0;
      *(u16x8*)(&lK[nxt][sr + 32][sw])  = kreg1;
      *(u16x8*)(&lVt[nxt][sr][sw])      = vreg0;
      *(u16x8*)(&lVt[nxt][sr + 32][sw]) = vreg1;
    }
  }

  // epilogues: reduce l across hi-copies once, normalize, store
  lA_ += __shfl_xor(lA_, 16, 64);
  lA_ += __shfl_xor(lA_, 32, 64);
  lB_ += __shfl_xor(lB_, 16, 64);
  lB_ += __shfl_xor(lB_, 32, 64);
  {
    float linv[4];
#pragma unroll
    for (int j = 0; j < 4; ++j) linv[j] = 1.0f / __shfl(lA_, 4 * hi + j, 64);
#pragma unroll
    for (int f = 0; f < 4; ++f)
#pragma unroll
      for (int j = 0; j < 4; ++j) {
        int row = qtA * 64 + w * 16 + hi * 4 + j;
        Ob[((size_t)(b * 2048 + row)) * 1024 + h * 64 + f * 16 + la] =
            f2b(aoA[f][j] * linv[j]);
      }
  }
  {
    float linv[4];
#pragma unroll
    for (int j = 0; j < 4; ++j) linv[j] = 1.0f / __shfl(lB_, 4 * hi + j, 64);
#pragma unroll
    for (int f = 0; f < 4; ++f)
#pragma unroll
      for (int j = 0; j < 4; ++j) {
        int row = qtB * 64 + w * 16 + hi * 4 + j;
        Ob[((size_t)(b * 2048 + row)) * 1024 + h * 64 + f * 16 + la] =
            f2b(aoB[f][j] * linv[j]);
      }
  }
}

extern "C" void kernel_launch(void* const* d_in, const int* in_sizes, int n_in,
                              void* d_out, int out_size, void* d_ws, size_t ws_size,
                              hipStream_t stream) {
  const float* x  = (const float*)d_in[0];   // (2,2048,1024) f32
  const float* wa = (const float*)d_in[1];   // (1024,1536)  f32
  const float* wp = (const float*)d_in[2];   // (1024,1024)  f32
  float* out = (float*)d_out;                // (2,2048,1024) f32
  char* ws = (char*)d_ws;
  u16* xb    = (u16*)(ws + 0);          // 4096x1024 bf16
  u16* waT   = (u16*)(ws + 8388608);    // 1536x1024 bf16
  u16* wpT   = (u16*)(ws + 11534336);   // 1024x1024 bf16
  u16* Qb    = (u16*)(ws + 26214400);   // [2][16][2048][64] bf16
  u16* Kb    = (u16*)(ws + 34603008);   // [2][4][2048][64] bf16
  u16* Vtb   = (u16*)(ws + 36700160);   // [2][4][64][2048] bf16
  u16* Ob    = (u16*)(ws + 38797312);   // 4096x1024 bf16
  float2* rt = (float2*)(ws + 47185920); // 2048x32 float2 (512KB)

  k_prep<<<4864, 256, 0, stream>>>(x, wa, wp, xb, waT, wpT, rt);
  k_gemm1<<<768, 256, 0, stream>>>(xb, waT, rt, Qb, Kb, Vtb);
  k_attn<<<512, 256, 0, stream>>>(Qb, Kb, Vtb, Ob);
  k_gemm_bt<0><<<512, 256, 0, stream>>>(Ob, wpT, out, 4096, 1024, 1024);
}